// Round 8
// baseline (82.785 us; speedup 1.0000x reference)
//
#include <hip/hip_runtime.h>

// Problem constants: v (targets y), v_pred (queries x) are [4, 8192, 3] fp32.
#define BB 4
#define NN 8192
#define MM 8192
#define BN (BB * NN)

#define BLK 256        // threads per block = 4 waves
#define QB  256        // queries per block = 8 A-tiles of 32 (2 per wave)
#define TC  1024       // targets per s-chunk = 32 B-tiles (32 KB LDS image)
#define S   (MM / TC)  // 8 s-chunks
#define NJT (TC / 32)  // 32 j-tiles per chunk
#define NGRP ((NN / QB) * BB)   // 128 groups
// grid (NN/QB, S, BB) = (32, 8, 4) = 1024 blocks = 4 blocks/CU, 16 waves/CU.

typedef __bf16 bf16x8 __attribute__((ext_vector_type(8)));
typedef float  f32x16 __attribute__((ext_vector_type(16)));

// ws layout: part: float[128 groups][8 s][256 q] per-query per-s min d2 (1 MB).
// All cross-block handoffs are kernel boundaries (in-stream order, no fences).
//
// v_mfma_f32_32x32x16_bf16 (layouts verified by R0/R2/R5/R6 absmax=0.0):
//   A: row=lane&31, k=(lane>>5)*8+e;  B: col=lane&31, k=(lane>>5)*8+e
//   D: col=lane&31, row=(r&3)+8*(r>>2)+4*(lane>>5)
// K-slot packing: k0..3 {2x0h,2x0h,2x0l,2x0l}x{y0h,y0l,y0h,y0l} = 2*x0*y0;
// k4..7 dim1; k8..11 dim2; k12,13 {-xx_h,-xx_l}x{1,1}; k14,15 {1,1}x{-yy_h,-yy_l}
// => with C=0: D = 2x.y - xx - yy = -d2.  min d2 = -max D.

static __device__ inline void split_bf(float v, __bf16& h, __bf16& l) {
    h = (__bf16)v;
    l = (__bf16)(v - (float)h);
}

__global__ __launch_bounds__(BLK, 4) void chamfer_part(
    const float* __restrict__ y,     // v      [B, M, 3] targets
    const float* __restrict__ x,     // v_pred [B, N, 3] queries
    float* __restrict__ part)        // ws [NGRP][S][QB]
{
    __shared__ uint4 FR[NJT * 64];   // 32 KB B image only (A never touches LDS)
    __shared__ float red[QB];

    const int t   = threadIdx.x;
    const int l   = t & 63;
    const int w   = t >> 6;          // wave 0..3
    const int hi  = l >> 5;          // frag part
    const int c32 = l & 31;
    const int ib  = blockIdx.x;      // query chunk 0..31
    const int s   = blockIdx.y;      // target chunk 0..7
    const int b   = blockIdx.z;      // batch
    const int g   = b * (NN / QB) + ib;   // group 0..127

    // ---- A fragments fully in-register. Thread t builds query t's frag
    //      parts (g0 = k0..7, g1 = k8..15). Wave w's queries are owned by
    //      wave w's own lanes, so 64-wide shuffles suffice.
    //      R7 BUG FIX: shuffles must run under UNIFORM control flow — a
    //      divergent `hi ? shfl : shfl` makes bpermute pull from inactive
    //      lanes (undefined on CDNA). Shuffle BOTH parts with all lanes
    //      active, then cndmask-select by dest-lane `hi`. ----
    bf16x8 a0, a1;
    {
        const float* xb = x + ((size_t)b * NN + (size_t)ib * QB) * 3;
        float x0 = xb[3*t+0], x1 = xb[3*t+1], x2 = xb[3*t+2];
        __bf16 h0,l0,h1,l1,h2,l2;
        split_bf(2.0f*x0, h0, l0);
        split_bf(2.0f*x1, h1, l1);
        split_bf(2.0f*x2, h2, l2);
        float nxx = -__builtin_fmaf(x2, x2, __builtin_fmaf(x1, x1, x0*x0));
        __bf16 hx, lx; split_bf(nxx, hx, lx);
        const __bf16 one = (__bf16)1.0f;
        bf16x8 g0 = {h0,h0,l0,l0,h1,h1,l1,l1};   // k-slots 0..7  (hi=0 part)
        bf16x8 g1 = {h2,h2,l2,l2,hx,lx,one,one}; // k-slots 8..15 (hi=1 part)
        uint4 u0 = __builtin_bit_cast(uint4, g0);
        uint4 u1 = __builtin_bit_cast(uint4, g1);

        // a0: part hi of query (64w + c32)  -> src lane c32
        int p0x = __shfl((int)u0.x, c32, 64), p1x = __shfl((int)u1.x, c32, 64);
        int p0y = __shfl((int)u0.y, c32, 64), p1y = __shfl((int)u1.y, c32, 64);
        int p0z = __shfl((int)u0.z, c32, 64), p1z = __shfl((int)u1.z, c32, 64);
        int p0w = __shfl((int)u0.w, c32, 64), p1w = __shfl((int)u1.w, c32, 64);
        // a1: part hi of query (64w + 32 + c32) -> src lane 32+c32
        int q0x = __shfl((int)u0.x, 32+c32, 64), q1x = __shfl((int)u1.x, 32+c32, 64);
        int q0y = __shfl((int)u0.y, 32+c32, 64), q1y = __shfl((int)u1.y, 32+c32, 64);
        int q0z = __shfl((int)u0.z, 32+c32, 64), q1z = __shfl((int)u1.z, 32+c32, 64);
        int q0w = __shfl((int)u0.w, 32+c32, 64), q1w = __shfl((int)u1.w, 32+c32, 64);

        uint4 r0, r1;
        r0.x = (unsigned)(hi ? p1x : p0x);  r0.y = (unsigned)(hi ? p1y : p0y);
        r0.z = (unsigned)(hi ? p1z : p0z);  r0.w = (unsigned)(hi ? p1w : p0w);
        r1.x = (unsigned)(hi ? q1x : q0x);  r1.y = (unsigned)(hi ? q1y : q0y);
        r1.z = (unsigned)(hi ? q1z : q0z);  r1.w = (unsigned)(hi ? q1w : q0w);
        a0 = __builtin_bit_cast(bf16x8, r0);
        a1 = __builtin_bit_cast(bf16x8, r1);
    }

    // ---- stage B fragment image: 1024 targets, 4 per thread ----
    {
        const float* yb = y + ((size_t)b * MM + (size_t)s * TC) * 3;
        const __bf16 one = (__bf16)1.0f;
#pragma unroll
        for (int k2 = 0; k2 < 4; ++k2) {
            const int j = t + k2 * BLK;
            float y0 = yb[3*j+0], y1 = yb[3*j+1], y2 = yb[3*j+2];
            __bf16 h0,l0,h1,l1,h2,l2;
            split_bf(y0, h0, l0);
            split_bf(y1, h1, l1);
            split_bf(y2, h2, l2);
            float nyy = -__builtin_fmaf(y2, y2, __builtin_fmaf(y1, y1, y0*y0));
            __bf16 hy, ly; split_bf(nyy, hy, ly);
            bf16x8 g0 = {h0,l0,h0,l0,h1,l1,h1,l1};
            bf16x8 g1 = {h2,l2,h2,l2,one,one,hy,ly};
            const int jt = j >> 5, col = j & 31;
            FR[jt*64 +      col] = __builtin_bit_cast(uint4, g0);
            FR[jt*64 + 32 + col] = __builtin_bit_cast(uint4, g1);
        }
    }
    __syncthreads();                 // ONE barrier total before the loop

    // ---- main loop: 2-pair-deep rotation prefetch hides ds_read latency ----
    f32x16 z;
#pragma unroll
    for (int r = 0; r < 16; ++r) z[r] = 0.0f;
    f32x16 best0, best1;
#pragma unroll
    for (int r = 0; r < 16; ++r) { best0[r] = -3.4e38f; best1[r] = -3.4e38f; }

    bf16x8 c0 = __builtin_bit_cast(bf16x8, FR[0*64 + l]);
    bf16x8 c1 = __builtin_bit_cast(bf16x8, FR[1*64 + l]);
    bf16x8 n0 = __builtin_bit_cast(bf16x8, FR[2*64 + l]);
    bf16x8 n1 = __builtin_bit_cast(bf16x8, FR[3*64 + l]);

#pragma unroll 1
    for (int jt = 0; jt < NJT; jt += 2) {
        // prefetch pair jt+4 (wrapped index on the tail; values unused then)
        bf16x8 f0 = __builtin_bit_cast(bf16x8, FR[((jt+4) & 31)*64 + l]);
        bf16x8 f1 = __builtin_bit_cast(bf16x8, FR[((jt+5) & 31)*64 + l]);
        f32x16 p = __builtin_amdgcn_mfma_f32_32x32x16_bf16(a0, c0, z, 0, 0, 0);
        f32x16 q = __builtin_amdgcn_mfma_f32_32x32x16_bf16(a0, c1, z, 0, 0, 0);
#pragma unroll
        for (int r = 0; r < 16; ++r)
            best0[r] = fmaxf(fmaxf(best0[r], p[r]), q[r]);   // v_max3_f32
        p = __builtin_amdgcn_mfma_f32_32x32x16_bf16(a1, c0, z, 0, 0, 0);
        q = __builtin_amdgcn_mfma_f32_32x32x16_bf16(a1, c1, z, 0, 0, 0);
#pragma unroll
        for (int r = 0; r < 16; ++r)
            best1[r] = fmaxf(fmaxf(best1[r], p[r]), q[r]);
        c0 = n0; c1 = n1; n0 = f0; n1 = f1;
    }

    // ---- col-reduce (32 targets) into LDS, then ONE coalesced store ----
#pragma unroll
    for (int ii = 0; ii < 2; ++ii) {
        const f32x16 bb = ii ? best1 : best0;
#pragma unroll
        for (int r = 0; r < 16; ++r) {
            float v = bb[r];
            v = fmaxf(v, __shfl_xor(v, 1, 64));
            v = fmaxf(v, __shfl_xor(v, 2, 64));
            v = fmaxf(v, __shfl_xor(v, 4, 64));
            v = fmaxf(v, __shfl_xor(v, 8, 64));
            v = fmaxf(v, __shfl_xor(v, 16, 64));
            if (c32 == 0) {
                const int qrow = (w*2 + ii)*32 + (r & 3) + 8*(r >> 2) + 4*hi;
                red[qrow] = -v;                 // min d2 for this (g, s, q)
            }
        }
    }
    __syncthreads();
    part[((size_t)g * S + s) * QB + t] = red[t];  // plain coalesced store
}

// Kernel 2: ONE block, 1024 threads: min over 8 s-slices, sum all 32768
// queries, write the mean. 1 MB of L2-resident reads, fully coalesced.
__global__ __launch_bounds__(1024) void reduce_one(
    const float* __restrict__ part,   // [NGRP][S][QB]
    float* __restrict__ out)
{
    const int t = threadIdx.x;
    const int q = t & 255;
    float acc = 0.0f;
#pragma unroll 2
    for (int i = 0; i < NGRP / 4; ++i) {
        const int gidx = (t >> 8) + 4 * i;
        const float* pg = part + (size_t)gidx * S * QB + q;
        float dq = pg[0];
#pragma unroll
        for (int ss = 1; ss < S; ++ss)
            dq = fminf(dq, pg[ss * QB]);
        acc += dq;
    }
    for (int off = 32; off > 0; off >>= 1)
        acc += __shfl_down(acc, off, 64);
    __shared__ float wsum[16];
    if ((t & 63) == 0) wsum[t >> 6] = acc;
    __syncthreads();
    if (t == 0) {
        float tot = 0.0f;
#pragma unroll
        for (int i = 0; i < 16; ++i) tot += wsum[i];
        out[0] = tot * (1.0f / (float)BN);
    }
}

extern "C" void kernel_launch(void* const* d_in, const int* in_sizes, int n_in,
                              void* d_out, int out_size, void* d_ws, size_t ws_size,
                              hipStream_t stream) {
    // setup_inputs order: d_in[0] = v (targets y), d_in[1] = v_pred (queries x)
    const float* v      = (const float*)d_in[0];
    const float* v_pred = (const float*)d_in[1];
    float* out = (float*)d_out;

    float* part = (float*)d_ws;                 // 1 MB

    chamfer_part<<<dim3(NN / QB, S, BB), BLK, 0, stream>>>(v, v_pred, part);
    reduce_one<<<1, 1024, 0, stream>>>(part, out);
}